// Round 1
// baseline (5443.700 us; speedup 1.0000x reference)
//
#include <hip/hip_runtime.h>
#include <hip/hip_bf16.h>
#include <stdint.h>
#include <stdio.h>

typedef __attribute__((ext_vector_type(8))) short bf16x8;
typedef __attribute__((ext_vector_type(4))) float f32x4;

#define SEQ   512
#define BATCH 256
#define INDIM 512
#define HID   256
#define NGATE 1024
#define M_TOT (SEQ*BATCH)

// workspace layout (bytes)
#define ZX_BYTES  ((size_t)M_TOT * NGATE * 2)         // 268435456  bf16 [M][1024]
#define WX_OFF    ZX_BYTES
#define WX_BYTES  ((size_t)NGATE * INDIM * 2)         // 1 MiB      bf16 [1024][512]
#define WHF_OFF   (WX_OFF + WX_BYTES)
#define WHF_BYTES ((size_t)NGATE * HID * 2)           // 512 KiB    frag-packed
#define BIAS_OFF  (WHF_OFF + WHF_BYTES)
#define WS_NEEDED (BIAS_OFF + NGATE*4)

__device__ __forceinline__ unsigned short f2bf(float x) {
    unsigned int u = __float_as_uint(x);
    u += 0x7fffu + ((u >> 16) & 1u);
    return (unsigned short)(u >> 16);
}
__device__ __forceinline__ float bf2f(unsigned short s) {
    return __uint_as_float(((unsigned int)s) << 16);
}

// ---------------------------------------------------------------------------
// Prep: convert weights to bf16; pack Wh into MFMA B-fragment order; pack bias.
// grid 1024 blocks (one per gate row n), 256 threads.
// ---------------------------------------------------------------------------
__global__ void prep_kernel(const float* __restrict__ Wf, const float* __restrict__ bfv,
                            const float* __restrict__ Wi, const float* __restrict__ biv,
                            const float* __restrict__ Wg, const float* __restrict__ bgv,
                            const float* __restrict__ Wo, const float* __restrict__ bov,
                            unsigned short* __restrict__ Wx,
                            unsigned short* __restrict__ WhF,
                            float* __restrict__ biasP)
{
    int n = blockIdx.x;              // 0..1023
    int gate = n >> 8, r = n & 255;
    const float* Wrow; const float* bv;
    if      (gate == 0) { Wrow = Wf; bv = bfv; }
    else if (gate == 1) { Wrow = Wi; bv = biv; }
    else if (gate == 2) { Wrow = Wg; bv = bgv; }
    else                { Wrow = Wo; bv = bov; }
    Wrow += (size_t)r * (INDIM + HID);
    int tid = threadIdx.x;

    // x-part: plain bf16 [n][k], row-major
    for (int k = tid; k < INDIM; k += 256)
        Wx[(size_t)n * INDIM + k] = f2bf(Wrow[k]);

    // h-part: B-fragment packing for mfma_f32_16x16x32_bf16
    // frag elem: lane l holds B[col = base+(l&15)][k = ks*32 + (l>>4)*8 + j]
    {
        int kk  = tid;                         // 0..255 (k within Wh)
        int ks  = kk >> 5, rem = kk & 31, hi = rem >> 3, j = rem & 7;
        int w   = r >> 5, qq = r & 31, sub = qq >> 4, coln = qq & 15;
        int tt  = gate * 2 + sub;
        int lane = hi * 16 + coln;
        size_t idx = ((((size_t)w * 8 + tt) * 8 + ks) * 64 + lane) * 8 + j;
        WhF[idx] = f2bf(Wrow[INDIM + kk]);
    }
    if (tid == 0) biasP[n] = bv[r];
}

// ---------------------------------------------------------------------------
// Phase 1: ZX[m][n] = bf16( X[m][:] @ Wx[n][:] + bias[n] ),  m = t*256+b
// 128x128 tile, BK=64, 4 waves (2x2 of 64x64), XOR-swizzled LDS.
// Block swizzle: 8 N-tiles sharing an A panel land on the same XCD.
// ---------------------------------------------------------------------------
__global__ __launch_bounds__(256) void zx_gemm(const float* __restrict__ X,
                                               const unsigned short* __restrict__ Wx,
                                               const float* __restrict__ biasP,
                                               unsigned short* __restrict__ ZX)
{
    int id = blockIdx.x;                              // 0..8191
    int by = (id & 7) | ((id >> 6) << 3);             // 0..1023 (M tile)
    int bx = (id >> 3) & 7;                           // 0..7    (N tile)
    int m0 = by * 128, n0 = bx * 128;

    __shared__ unsigned short Alds[128 * 64];
    __shared__ unsigned short Blds[128 * 64];

    int tid = threadIdx.x;
    int lane = tid & 63, wave = tid >> 6;
    int wm = wave >> 1, wn = wave & 1;
    int cl = lane & 15, hi = lane >> 4;

    f32x4 acc[4][4];
#pragma unroll
    for (int a = 0; a < 4; a++)
#pragma unroll
        for (int b = 0; b < 4; b++) acc[a][b] = (f32x4){0.f, 0.f, 0.f, 0.f};

    for (int kt = 0; kt < 8; ++kt) {
        int k0 = kt * 64;
        // stage A (fp32 -> bf16), swizzled
#pragma unroll
        for (int i = 0; i < 8; ++i) {
            int idx = i * 256 + tid;                  // 0..2047 (16B fp32 chunks)
            int row = idx >> 4;
            int seg = idx & 15;
            const float4 v = *(const float4*)(X + (size_t)(m0 + row) * INDIM + k0 + seg * 4);
            unsigned long long pk = (unsigned long long)f2bf(v.x)
                                  | ((unsigned long long)f2bf(v.y) << 16)
                                  | ((unsigned long long)f2bf(v.z) << 32)
                                  | ((unsigned long long)f2bf(v.w) << 48);
            int dstb = row * 128 + ((seg * 8) ^ ((row & 7) << 4));
            *(unsigned long long*)((char*)Alds + dstb) = pk;
        }
        // stage B (already bf16), swizzled
#pragma unroll
        for (int i = 0; i < 4; ++i) {
            int c = i * 256 + tid;                    // 0..1023 (16B chunks)
            int nrow = c >> 3, koff = c & 7;
            uint4 u = *(const uint4*)((const char*)Wx + (size_t)(n0 + nrow) * (INDIM * 2) + k0 * 2 + koff * 16);
            int dstb = nrow * 128 + ((koff * 16) ^ ((nrow & 7) << 4));
            *(uint4*)((char*)Blds + dstb) = u;
        }
        __syncthreads();
#pragma unroll
        for (int ks = 0; ks < 2; ++ks) {
            int kb = ks * 64 + hi * 16;
            bf16x8 af[4], bg[4];
#pragma unroll
            for (int tm = 0; tm < 4; tm++) {
                int row = wm * 64 + tm * 16 + cl;
                af[tm] = *(const bf16x8*)((char*)Alds + row * 128 + (kb ^ ((row & 7) << 4)));
            }
#pragma unroll
            for (int tn = 0; tn < 4; tn++) {
                int nr = wn * 64 + tn * 16 + cl;
                bg[tn] = *(const bf16x8*)((char*)Blds + nr * 128 + (kb ^ ((nr & 7) << 4)));
            }
#pragma unroll
            for (int tm = 0; tm < 4; tm++)
#pragma unroll
                for (int tn = 0; tn < 4; tn++)
                    acc[tm][tn] = __builtin_amdgcn_mfma_f32_16x16x32_bf16(af[tm], bg[tn], acc[tm][tn], 0, 0, 0);
        }
        __syncthreads();
    }
    // epilogue: + bias, cvt bf16, store
#pragma unroll
    for (int tn = 0; tn < 4; tn++) {
        int col = n0 + wn * 64 + tn * 16 + cl;
        float bias = biasP[col];
#pragma unroll
        for (int tm = 0; tm < 4; tm++) {
#pragma unroll
            for (int r = 0; r < 4; r++) {
                int row = m0 + wm * 64 + tm * 16 + hi * 4 + r;
                ZX[(size_t)row * NGATE + col] = f2bf(acc[tm][tn][r] + bias);
            }
        }
    }
}

// ---------------------------------------------------------------------------
// Phase 2: batch-parallel recurrence. 16 blocks x 512 threads (8 waves).
// Block = 16 batch rows (M=16). Wave w owns hidden slice q in [32w, 32w+32).
// Per step: z = ZX[t] + h @ Wh^T (MFMA, B-frags streamed from L2-resident
// packed WhF), gates on VALU, c/h update in regs, h -> swizzled LDS (bf16).
// Zero inter-block communication.
// ---------------------------------------------------------------------------
__global__ __launch_bounds__(512, 2) void recurrence(const unsigned short* __restrict__ ZX,
                                                     const unsigned short* __restrict__ WhFu,
                                                     float* __restrict__ out)
{
    int blk  = blockIdx.x;                 // 0..15
    int tid  = threadIdx.x;
    int lane = tid & 63, wave = tid >> 6;  // wave 0..7
    int cl   = lane & 15, hi = lane >> 4;

    __shared__ unsigned short hbuf[2][16 * 256];   // double-buffered h (bf16, swizzled)
    {
        uint4 z4 = make_uint4(0, 0, 0, 0);
        uint4* p = (uint4*)hbuf;
#pragma unroll
        for (int i = 0; i < 2; i++) p[i * 512 + tid] = z4;   // 16 KiB total
    }
    __syncthreads();

    float c_s[2][4], h_l[2][4];
#pragma unroll
    for (int s = 0; s < 2; s++)
#pragma unroll
        for (int r = 0; r < 4; r++) { c_s[s][r] = 0.f; h_l[s][r] = 0.f; }

    const bf16x8* WhF = (const bf16x8*)WhFu;
    const bf16x8* wb  = WhF + (size_t)wave * 4096 + lane;   // ((wave*8+tt)*8+ks)*64 + lane

    int ncol[8];
#pragma unroll
    for (int tt = 0; tt < 8; tt++)
        ncol[tt] = (tt >> 1) * 256 + wave * 32 + (tt & 1) * 16 + cl;

    int mrow_base = blk * 16 + hi * 4;     // + r

    // preload ZX for t=0
    unsigned short zxc[8][4];
    {
        const unsigned short* zr = ZX + ((size_t)0 * BATCH + mrow_base) * NGATE;
#pragma unroll
        for (int tt = 0; tt < 8; tt++)
#pragma unroll
            for (int r = 0; r < 4; r++)
                zxc[tt][r] = zr[(size_t)r * NGATE + ncol[tt]];
    }

#pragma unroll 1
    for (int t = 0; t < SEQ; ++t) {
        // prefetch next step's ZX (clamped dummy at t=511)
        int tn_ = (t + 1 < SEQ) ? (t + 1) : t;
        const unsigned short* zr = ZX + ((size_t)tn_ * BATCH + mrow_base) * NGATE;
        unsigned short zxn[8][4];
#pragma unroll
        for (int tt = 0; tt < 8; tt++)
#pragma unroll
            for (int r = 0; r < 4; r++)
                zxn[tt][r] = zr[(size_t)r * NGATE + ncol[tt]];

        // A-fragments of h from LDS (swizzled)
        const char* hb = (const char*)hbuf[t & 1];
        bf16x8 af[8];
#pragma unroll
        for (int ks = 0; ks < 8; ks++)
            af[ks] = *(const bf16x8*)(hb + cl * 512 + ((ks * 64 + hi * 16) ^ (cl << 4)));

        // acc init from ZX (includes bias)
        f32x4 acc[8];
#pragma unroll
        for (int tt = 0; tt < 8; tt++) {
            f32x4 a;
            a[0] = bf2f(zxc[tt][0]); a[1] = bf2f(zxc[tt][1]);
            a[2] = bf2f(zxc[tt][2]); a[3] = bf2f(zxc[tt][3]);
            acc[tt] = a;
        }

        // z += h @ Wh^T : ping-pong B-frag loads, 64 MFMA
        bf16x8 bcur[8], bnxt[8];
#pragma unroll
        for (int tt = 0; tt < 8; tt++) bcur[tt] = wb[tt * 8 * 64];
#pragma unroll
        for (int ks = 0; ks < 8; ks++) {
            if (ks < 7) {
#pragma unroll
                for (int tt = 0; tt < 8; tt++) bnxt[tt] = wb[(tt * 8 + ks + 1) * 64];
            }
#pragma unroll
            for (int tt = 0; tt < 8; tt++)
                acc[tt] = __builtin_amdgcn_mfma_f32_16x16x32_bf16(af[ks], bcur[tt], acc[tt], 0, 0, 0);
#pragma unroll
            for (int tt = 0; tt < 8; tt++) bcur[tt] = bnxt[tt];
        }

        // gates + state update + h store
        char* hw = (char*)hbuf[(t + 1) & 1];
#pragma unroll
        for (int sub = 0; sub < 2; ++sub) {
#pragma unroll
            for (int r = 0; r < 4; r++) {
                float zf = -__sinf(acc[0 + sub][r]);
                float zi = -__sinf(acc[2 + sub][r]);
                float zg = -__sinf(acc[4 + sub][r]);
                float zo = -__sinf(acc[6 + sub][r]);
                float fg = 1.f / (1.f + __expf(-zf));
                float ig = 1.f / (1.f + __expf(-zi));
                float eg = __expf(2.f * zg);
                float gg = (eg - 1.f) / (eg + 1.f);
                float og = 1.f / (1.f + __expf(-zo));
                float c  = fg * c_s[sub][r] + ig * gg;
                c_s[sub][r] = c;
                float ec = __expf(2.f * c);
                float h  = og * ((ec - 1.f) / (ec + 1.f));
                h_l[sub][r] = h;
                int m = hi * 4 + r;
                int q = wave * 32 + sub * 16 + cl;
                *(unsigned short*)(hw + m * 512 + ((q * 2) ^ (m << 4))) = f2bf(h);
                out[((size_t)t * BATCH + blk * 16 + m) * HID + q] = h;
            }
        }
        // roll prefetched ZX
#pragma unroll
        for (int tt = 0; tt < 8; tt++)
#pragma unroll
            for (int r = 0; r < 4; r++) zxc[tt][r] = zxn[tt][r];

        __syncthreads();
    }

    // final hx, cx
    size_t base = (size_t)SEQ * BATCH * HID;
#pragma unroll
    for (int sub = 0; sub < 2; sub++)
#pragma unroll
        for (int r = 0; r < 4; r++) {
            int m = blk * 16 + hi * 4 + r;
            int q = wave * 32 + sub * 16 + cl;
            out[base + (size_t)m * HID + q] = h_l[sub][r];
            out[base + (size_t)BATCH * HID + (size_t)m * HID + q] = c_s[sub][r];
        }
}

// ---------------------------------------------------------------------------
extern "C" void kernel_launch(void* const* d_in, const int* in_sizes, int n_in,
                              void* d_out, int out_size, void* d_ws, size_t ws_size,
                              hipStream_t stream)
{
    const float* X   = (const float*)d_in[0];
    const float* Wf  = (const float*)d_in[1];
    const float* bfv = (const float*)d_in[2];
    const float* Wi  = (const float*)d_in[3];
    const float* biv = (const float*)d_in[4];
    const float* Wg  = (const float*)d_in[5];
    const float* bgv = (const float*)d_in[6];
    const float* Wo  = (const float*)d_in[7];
    const float* bov = (const float*)d_in[8];

    if (ws_size < WS_NEEDED) {
        fprintf(stderr, "kernel_launch: ws_size=%zu < needed %zu\n", ws_size, (size_t)WS_NEEDED);
        return;
    }

    char* ws = (char*)d_ws;
    unsigned short* ZX    = (unsigned short*)(ws);
    unsigned short* Wx    = (unsigned short*)(ws + WX_OFF);
    unsigned short* WhF   = (unsigned short*)(ws + WHF_OFF);
    float*          biasP = (float*)(ws + BIAS_OFF);
    float*          out   = (float*)d_out;

    prep_kernel<<<dim3(1024), dim3(256), 0, stream>>>(Wf, bfv, Wi, biv, Wg, bgv, Wo, bov,
                                                      Wx, WhF, biasP);
    zx_gemm<<<dim3(8192), dim3(256), 0, stream>>>(X, Wx, biasP, ZX);
    recurrence<<<dim3(16), dim3(512), 0, stream>>>(ZX, WhF, out);
}

// Round 2
// 3396.054 us; speedup vs baseline: 1.6029x; 1.6029x over previous
//
#include <hip/hip_runtime.h>
#include <hip/hip_bf16.h>
#include <stdint.h>
#include <stdio.h>

typedef __attribute__((ext_vector_type(8))) short bf16x8;
typedef __attribute__((ext_vector_type(4))) float f32x4;

#define SEQ   512
#define BATCH 256
#define INDIM 512
#define HID   256
#define NGATE 1024
#define M_TOT (SEQ*BATCH)

// workspace layout (bytes)
#define ZX_BYTES  ((size_t)M_TOT * NGATE * 2)         // 268435456  bf16 [M][1024]
#define WX_OFF    ZX_BYTES
#define WX_BYTES  ((size_t)NGATE * INDIM * 2)         // 1 MiB      bf16 [1024][512]
#define WHF_OFF   (WX_OFF + WX_BYTES)
#define WHF_BYTES ((size_t)NGATE * HID * 2)           // 512 KiB    frag-packed
#define BIAS_OFF  (WHF_OFF + WHF_BYTES)
#define WS_NEEDED (BIAS_OFF + NGATE*4)
// h-exchange + sync counters OVERLAY the Wx region (Wx dead after zx_gemm).
#define HEX_OFF   WX_OFF
#define HEX_BYTES ((size_t)2 * 16 * 8 * 512 * 2)      // 262144: [par][bg][ks][lane][j] bf16
#define CNT_OFF   (HEX_OFF + HEX_BYTES)
#define CNT_BYTES 4096

__device__ __forceinline__ unsigned short f2bf(float x) {
    unsigned int u = __float_as_uint(x);
    u += 0x7fffu + ((u >> 16) & 1u);
    return (unsigned short)(u >> 16);
}
__device__ __forceinline__ float bf2f(unsigned short s) {
    return __uint_as_float(((unsigned int)s) << 16);
}

// ---------------------------------------------------------------------------
// Prep: convert weights to bf16; pack Wh into per-(qslice,wave) MFMA B-frag
// order; pack bias. grid 1024 blocks (one per gate row n), 256 threads.
// ---------------------------------------------------------------------------
__global__ void prep_kernel(const float* __restrict__ Wf, const float* __restrict__ bfv,
                            const float* __restrict__ Wi, const float* __restrict__ biv,
                            const float* __restrict__ Wg, const float* __restrict__ bgv,
                            const float* __restrict__ Wo, const float* __restrict__ bov,
                            unsigned short* __restrict__ Wx,
                            unsigned short* __restrict__ WhF,
                            float* __restrict__ biasP)
{
    int n = blockIdx.x;              // 0..1023
    int gate = n >> 8, q = n & 255;  // q = hidden row within gate
    const float* Wrow; const float* bv;
    if      (gate == 0) { Wrow = Wf; bv = bfv; }
    else if (gate == 1) { Wrow = Wi; bv = biv; }
    else if (gate == 2) { Wrow = Wg; bv = bgv; }
    else                { Wrow = Wo; bv = bov; }
    Wrow += (size_t)q * (INDIM + HID);
    int tid = threadIdx.x;

    // x-part: plain bf16 [n][k], row-major
    for (int k = tid; k < INDIM; k += 256)
        Wx[(size_t)n * INDIM + k] = f2bf(Wrow[k]);

    // h-part: B-frag packing keyed to recurrence ownership:
    // [qs(4)][w(8)][tt(2)][ks(8)][lane(64)][j(8)]
    {
        int k  = tid;                          // 0..255
        int qs = q >> 6, ql = q & 63, qt = ql >> 4, cl = ql & 15;
        int w  = gate * 2 + (qt >> 1), tt = qt & 1;
        int ks = k >> 5, hh = (k >> 3) & 3, j = k & 7;
        int lane = hh * 16 + cl;
        size_t idx = ((((size_t)(qs * 8 + w) * 2 + tt) * 8 + ks) * 64 + lane) * 8 + j;
        WhF[idx] = f2bf(Wrow[INDIM + k]);
    }
    if (tid == 0) biasP[n] = bv[q];
}

// ---------------------------------------------------------------------------
// Phase 1: ZX[m][n] = bf16( X[m][:] @ Wx[n][:] + bias[n] ),  m = t*256+b
// (unchanged from round 0 — verified)
// ---------------------------------------------------------------------------
__global__ __launch_bounds__(256) void zx_gemm(const float* __restrict__ X,
                                               const unsigned short* __restrict__ Wx,
                                               const float* __restrict__ biasP,
                                               unsigned short* __restrict__ ZX)
{
    int id = blockIdx.x;
    int by = (id & 7) | ((id >> 6) << 3);
    int bx = (id >> 3) & 7;
    int m0 = by * 128, n0 = bx * 128;

    __shared__ unsigned short Alds[128 * 64];
    __shared__ unsigned short Blds[128 * 64];

    int tid = threadIdx.x;
    int lane = tid & 63, wave = tid >> 6;
    int wm = wave >> 1, wn = wave & 1;
    int cl = lane & 15, hi = lane >> 4;

    f32x4 acc[4][4];
#pragma unroll
    for (int a = 0; a < 4; a++)
#pragma unroll
        for (int b = 0; b < 4; b++) acc[a][b] = (f32x4){0.f, 0.f, 0.f, 0.f};

    for (int kt = 0; kt < 8; ++kt) {
        int k0 = kt * 64;
#pragma unroll
        for (int i = 0; i < 8; ++i) {
            int idx = i * 256 + tid;
            int row = idx >> 4;
            int seg = idx & 15;
            const float4 v = *(const float4*)(X + (size_t)(m0 + row) * INDIM + k0 + seg * 4);
            unsigned long long pk = (unsigned long long)f2bf(v.x)
                                  | ((unsigned long long)f2bf(v.y) << 16)
                                  | ((unsigned long long)f2bf(v.z) << 32)
                                  | ((unsigned long long)f2bf(v.w) << 48);
            int dstb = row * 128 + ((seg * 8) ^ ((row & 7) << 4));
            *(unsigned long long*)((char*)Alds + dstb) = pk;
        }
#pragma unroll
        for (int i = 0; i < 4; ++i) {
            int c = i * 256 + tid;
            int nrow = c >> 3, koff = c & 7;
            uint4 u = *(const uint4*)((const char*)Wx + (size_t)(n0 + nrow) * (INDIM * 2) + k0 * 2 + koff * 16);
            int dstb = nrow * 128 + ((koff * 16) ^ ((nrow & 7) << 4));
            *(uint4*)((char*)Blds + dstb) = u;
        }
        __syncthreads();
#pragma unroll
        for (int ks = 0; ks < 2; ++ks) {
            int kb = ks * 64 + hi * 16;
            bf16x8 af[4], bg[4];
#pragma unroll
            for (int tm = 0; tm < 4; tm++) {
                int row = wm * 64 + tm * 16 + cl;
                af[tm] = *(const bf16x8*)((char*)Alds + row * 128 + (kb ^ ((row & 7) << 4)));
            }
#pragma unroll
            for (int tn = 0; tn < 4; tn++) {
                int nr = wn * 64 + tn * 16 + cl;
                bg[tn] = *(const bf16x8*)((char*)Blds + nr * 128 + (kb ^ ((nr & 7) << 4)));
            }
#pragma unroll
            for (int tm = 0; tm < 4; tm++)
#pragma unroll
                for (int tn = 0; tn < 4; tn++)
                    acc[tm][tn] = __builtin_amdgcn_mfma_f32_16x16x32_bf16(af[tm], bg[tn], acc[tm][tn], 0, 0, 0);
        }
        __syncthreads();
    }
#pragma unroll
    for (int tn = 0; tn < 4; tn++) {
        int col = n0 + wn * 64 + tn * 16 + cl;
        float bias = biasP[col];
#pragma unroll
        for (int tm = 0; tm < 4; tm++) {
#pragma unroll
            for (int r = 0; r < 4; r++) {
                int row = m0 + wm * 64 + tm * 16 + hi * 4 + r;
                ZX[(size_t)row * NGATE + col] = f2bf(acc[tm][tn][r] + bias);
            }
        }
    }
}

// ---------------------------------------------------------------------------
// Phase 2: recurrence, Wh register-resident.
// 64 blocks = 16 batch-groups (16 rows) x 4 hidden-slices (64 q each).
// Block (bg,qs): waves w=0..7 own gate g=w>>1, q-subtiles qt=(w&1)*2+tt.
// Per step: z = ZX + h @ Wh_slice (16 MFMA/wave, B in regs), z -> LDS,
// gate-combine, h-slice -> LLC exchange buffer, 4-block barrier.
// ---------------------------------------------------------------------------
__global__ __launch_bounds__(512, 2) void recurrence(const unsigned short* __restrict__ ZX,
                                                     const unsigned short* __restrict__ WhFu,
                                                     float* __restrict__ out,
                                                     unsigned short* __restrict__ hex,
                                                     unsigned int* __restrict__ cnt)
{
    int blk = blockIdx.x;                 // 0..63
    int bg = blk >> 2, qs = blk & 3;
    int tid = threadIdx.x;
    int lane = tid & 63, w = tid >> 6;    // wave 0..7
    int cl = lane & 15, hi = lane >> 4;

    __shared__ float zlds[256 * 20];      // [col 0..255][row stride 20]

    // -- B fragments: register-resident for all 512 steps --
    bf16x8 wb[2][8];
    {
        const bf16x8* wf = (const bf16x8*)WhFu + ((size_t)(qs * 8 + w) * 2) * 8 * 64 + lane;
#pragma unroll
        for (int tt = 0; tt < 2; tt++)
#pragma unroll
            for (int ks = 0; ks < 8; ks++)
                wb[tt][ks] = wf[(tt * 8 + ks) * 64];
    }

    int ncol[2];
#pragma unroll
    for (int tt = 0; tt < 2; tt++) {
        int ct = w * 2 + tt;
        ncol[tt] = (ct >> 2) * 256 + qs * 64 + (ct & 3) * 16 + cl;
    }
    int mbase = bg * 16 + hi * 4;

    float cst[2] = {0.f, 0.f}, hl[2] = {0.f, 0.f};

    // preload ZX for t=0
    unsigned short zxc[2][4];
    {
        const unsigned short* zr = ZX + ((size_t)0 * BATCH + mbase) * NGATE;
#pragma unroll
        for (int tt = 0; tt < 2; tt++)
#pragma unroll
            for (int r = 0; r < 4; r++)
                zxc[tt][r] = zr[(size_t)r * NGATE + ncol[tt]];
    }

#pragma unroll 1
    for (int t = 0; t < SEQ; ++t) {
        // ---- wait for peers' h(t) ----
        if (t > 0) {
            if (tid == 0) {
                unsigned int target = 4u * (unsigned)t;
                int guard = 0;
                while (__hip_atomic_load(&cnt[bg], __ATOMIC_RELAXED, __HIP_MEMORY_SCOPE_AGENT) < target) {
                    __builtin_amdgcn_s_sleep(2);
                    if (++guard > (1 << 26)) break;   // anti-deadlock safety
                }
                __builtin_amdgcn_fence(__ATOMIC_ACQUIRE, "agent");  // invalidate L1/L2
            }
            __syncthreads();
        }

        // ---- A fragments of h(t) from exchange buffer ----
        const bf16x8* hrd = (const bf16x8*)hex + (((size_t)(t & 1) * 16 + bg) * 8) * 64 + lane;
        bf16x8 af[8];
#pragma unroll
        for (int ks = 0; ks < 8; ks++) af[ks] = hrd[ks * 64];

        // ---- prefetch next step's ZX ----
        int tn_ = (t + 1 < SEQ) ? (t + 1) : t;
        const unsigned short* zr = ZX + ((size_t)tn_ * BATCH + mbase) * NGATE;
        unsigned short zxn[2][4];
#pragma unroll
        for (int tt = 0; tt < 2; tt++)
#pragma unroll
            for (int r = 0; r < 4; r++)
                zxn[tt][r] = zr[(size_t)r * NGATE + ncol[tt]];

        // ---- z = zx + h @ Wh^T ----
        f32x4 acc[2];
#pragma unroll
        for (int tt = 0; tt < 2; tt++) {
            f32x4 a;
            a[0] = bf2f(zxc[tt][0]); a[1] = bf2f(zxc[tt][1]);
            a[2] = bf2f(zxc[tt][2]); a[3] = bf2f(zxc[tt][3]);
            acc[tt] = a;
        }
#pragma unroll
        for (int ks = 0; ks < 8; ks++) {
            acc[0] = __builtin_amdgcn_mfma_f32_16x16x32_bf16(af[ks], wb[0][ks], acc[0], 0, 0, 0);
            acc[1] = __builtin_amdgcn_mfma_f32_16x16x32_bf16(af[ks], wb[1][ks], acc[1], 0, 0, 0);
        }

        // ---- z to LDS (block-local col = g*64 + qt*16 + cl) ----
#pragma unroll
        for (int tt = 0; tt < 2; tt++) {
            int ct = w * 2 + tt;
            int c  = (ct >> 2) * 64 + (ct & 3) * 16 + cl;
            *(f32x4*)&zlds[c * 20 + hi * 4] = acc[tt];
        }
        __syncthreads();

        // ---- gate combine + state update + h publish ----
        int p2 = (t + 1) & 1;
#pragma unroll
        for (int p = 0; p < 2; ++p) {
            int idx = tid + (p << 9);
            int ql = idx >> 4, m = idx & 15;
            float zf = -__sinf(zlds[(0 * 64 + ql) * 20 + m]);
            float zi = -__sinf(zlds[(1 * 64 + ql) * 20 + m]);
            float zg = -__sinf(zlds[(2 * 64 + ql) * 20 + m]);
            float zo = -__sinf(zlds[(3 * 64 + ql) * 20 + m]);
            float fg = 1.f / (1.f + __expf(-zf));
            float ig = 1.f / (1.f + __expf(-zi));
            float eg = __expf(2.f * zg);
            float gg = (eg - 1.f) / (eg + 1.f);
            float og = 1.f / (1.f + __expf(-zo));
            float c  = fg * cst[p] + ig * gg;
            cst[p] = c;
            float ec = __expf(2.f * c);
            float h  = og * ((ec - 1.f) / (ec + 1.f));
            hl[p] = h;
            out[((size_t)t * BATCH + bg * 16 + m) * HID + qs * 64 + ql] = h;
            int q  = qs * 64 + ql;
            int ks = q >> 5, hh = (q >> 3) & 3, j = q & 7, ln = hh * 16 + m;
            hex[(((size_t)p2 * 16 + bg) * 8 + ks) * 512 + ln * 8 + j] = f2bf(h);
        }
        __syncthreads();   // drains this block's stores (vmcnt 0 before barrier)

        // ---- publish arrival (release) ----
        if (tid == 0) {
            __builtin_amdgcn_fence(__ATOMIC_RELEASE, "agent");  // wbl2: flush to LLC
            atomicAdd(&cnt[bg], 1u);
        }

#pragma unroll
        for (int tt = 0; tt < 2; tt++)
#pragma unroll
            for (int r = 0; r < 4; r++) zxc[tt][r] = zxn[tt][r];
    }

    // final hx, cx
    size_t hxoff = (size_t)SEQ * BATCH * HID;
#pragma unroll
    for (int p = 0; p < 2; ++p) {
        int idx = tid + (p << 9);
        int ql = idx >> 4, m = idx & 15;
        out[hxoff + (size_t)(bg * 16 + m) * HID + qs * 64 + ql] = hl[p];
        out[hxoff + (size_t)BATCH * HID + (size_t)(bg * 16 + m) * HID + qs * 64 + ql] = cst[p];
    }
}

// ---------------------------------------------------------------------------
extern "C" void kernel_launch(void* const* d_in, const int* in_sizes, int n_in,
                              void* d_out, int out_size, void* d_ws, size_t ws_size,
                              hipStream_t stream)
{
    const float* X   = (const float*)d_in[0];
    const float* Wf  = (const float*)d_in[1];
    const float* bfv = (const float*)d_in[2];
    const float* Wi  = (const float*)d_in[3];
    const float* biv = (const float*)d_in[4];
    const float* Wg  = (const float*)d_in[5];
    const float* bgv = (const float*)d_in[6];
    const float* Wo  = (const float*)d_in[7];
    const float* bov = (const float*)d_in[8];

    if (ws_size < WS_NEEDED) {
        fprintf(stderr, "kernel_launch: ws_size=%zu < needed %zu\n", ws_size, (size_t)WS_NEEDED);
        return;
    }

    char* ws = (char*)d_ws;
    unsigned short* ZX    = (unsigned short*)(ws);
    unsigned short* Wx    = (unsigned short*)(ws + WX_OFF);
    unsigned short* WhF   = (unsigned short*)(ws + WHF_OFF);
    float*          biasP = (float*)(ws + BIAS_OFF);
    unsigned short* hex   = (unsigned short*)(ws + HEX_OFF);
    unsigned int*   cnt   = (unsigned int*)(ws + CNT_OFF);
    float*          out   = (float*)d_out;

    prep_kernel<<<dim3(1024), dim3(256), 0, stream>>>(Wf, bfv, Wi, biv, Wg, bgv, Wo, bov,
                                                      Wx, WhF, biasP);
    zx_gemm<<<dim3(8192), dim3(256), 0, stream>>>(X, Wx, biasP, ZX);
    // Wx region is dead now; zero the overlaid h-exchange + barrier counters.
    hipMemsetAsync(ws + HEX_OFF, 0, HEX_BYTES + CNT_BYTES, stream);
    recurrence<<<dim3(64), dim3(512), 0, stream>>>(ZX, WhF, out, hex, cnt);
}